// Round 4
// baseline (3777.106 us; speedup 1.0000x reference)
//
#include <hip/hip_runtime.h>
#include <hip/hip_bf16.h>
#include <math.h>

#define N_FEAT 32
#define N_HID  64   // 2*N_FEAT
#define N_LAT  64
#define R_HID  128  // 2*N_LAT
#define TPT    8    // tracks per thread (contiguous -> exploits sorted ids)

// ext_vector values are SSA (never demoted to scratch with constant indices).
typedef float f32x16 __attribute__((ext_vector_type(16)));
typedef float f32x4  __attribute__((ext_vector_type(4)));

// ---------------------------------------------------------------------------
// Kernel 1: fused phi MLP + segment-sum pooling.
// Weights staged in LDS: wave-uniform ds_read broadcasts are in-order
// (fine-grained lgkmcnt pipelining), unlike SMEM s_load which is out-of-order
// and forces lgkmcnt(0) drains (round-3 rocprof: VALUBusy 17%, latency-bound
// on s_load round trips). All per-thread state is named ext-vectors.
// ---------------------------------------------------------------------------
__global__ __launch_bounds__(256, 2) void phi_pool_kernel(
    const float* __restrict__ x,
    const int*   __restrict__ eids,
    const float* __restrict__ w1, const float* __restrict__ b1,
    const float* __restrict__ w2, const float* __restrict__ b2,
    float* __restrict__ pooled, int n_tracks)
{
    __shared__ float lw1[N_FEAT * N_HID + N_HID];   // w1 (2048) + b1 (64)
    __shared__ float lw2[N_HID * N_LAT + N_LAT];    // w2 (4096) + b2 (64)
    {
        int tid = threadIdx.x;
        for (int i = tid; i < N_FEAT * N_HID; i += 256) lw1[i] = w1[i];
        if (tid < N_HID) lw1[N_FEAT * N_HID + tid] = b1[tid];
        for (int i = tid; i < N_HID * N_LAT; i += 256) lw2[i] = w2[i];
        if (tid < N_LAT) lw2[N_HID * N_LAT + tid] = b2[tid];
    }
    __syncthreads();
    const float* lb1 = lw1 + N_FEAT * N_HID;
    const float* lb2 = lw2 + N_HID * N_LAT;

    long long start = (long long)(blockIdx.x * blockDim.x + threadIdx.x) * TPT;
    if (start >= n_tracks) return;

    f32x16 acc0, acc1, acc2, acc3;   // per-event pooled accumulator (64)
    #pragma unroll
    for (int i = 0; i < 16; ++i) { acc0[i] = 0.f; acc1[i] = 0.f; acc2[i] = 0.f; acc3[i] = 0.f; }
    int cur = -1;

    #pragma unroll 1
    for (int t = 0; t < TPT; ++t) {
        long long tr = start + t;
        if (tr >= n_tracks) break;
        int e = eids[tr];
        if (e != cur) {
            if (cur >= 0) {
                float* dst = pooled + (size_t)cur * N_LAT;
                #pragma unroll
                for (int mm = 0; mm < 16; ++mm) {
                    atomicAdd(dst + mm,      acc0[mm]);
                    atomicAdd(dst + 16 + mm, acc1[mm]);
                    atomicAdd(dst + 32 + mm, acc2[mm]);
                    atomicAdd(dst + 48 + mm, acc3[mm]);
                }
            }
            cur = e;
            #pragma unroll
            for (int i = 0; i < 16; ++i) { acc0[i] = 0.f; acc1[i] = 0.f; acc2[i] = 0.f; acc3[i] = 0.f; }
        }

        // x row (32 floats) in 8 named f32x4
        const f32x4* xp = reinterpret_cast<const f32x4*>(x + (size_t)tr * N_FEAT);
        f32x4 xv0 = xp[0], xv1 = xp[1], xv2 = xp[2], xv3 = xp[3],
              xv4 = xp[4], xv5 = xp[5], xv6 = xp[6], xv7 = xp[7];

        f32x16 h2_0, h2_1, h2_2, h2_3;   // pre-bias layer-2 accumulator (64)
        #pragma unroll
        for (int i = 0; i < 16; ++i) { h2_0[i] = 0.f; h2_1[i] = 0.f; h2_2[i] = 0.f; h2_3[i] = 0.f; }

        // rolled over 4 groups of 16 h1 outputs (I-cache: body ~2k instrs)
        #pragma unroll 1
        for (int g = 0; g < 4; ++g) {
            const int jbase = g * 16;
            f32x16 h1g;
            {
                const float* lbg = lb1 + jbase;
                f32x4 ba = *(const f32x4*)(lbg),     bb = *(const f32x4*)(lbg + 4),
                      bc = *(const f32x4*)(lbg + 8), bd = *(const f32x4*)(lbg + 12);
                #pragma unroll
                for (int q = 0; q < 4; ++q) {
                    h1g[q] = ba[q]; h1g[4+q] = bb[q]; h1g[8+q] = bc[q]; h1g[12+q] = bd[q];
                }
            }

            // layer 1, group g: h1g += x . W1[:, jbase..jbase+15]  (LDS vector reads)
            #define L1K(XV, KBASE)                                                    \
                _Pragma("unroll")                                                     \
                for (int kk = 0; kk < 4; ++kk) {                                      \
                    float xk = (XV)[kk];                                              \
                    const float* wr = lw1 + (size_t)((KBASE) + kk) * N_HID + jbase;   \
                    f32x4 wa = *(const f32x4*)(wr),     wb = *(const f32x4*)(wr + 4), \
                          wc = *(const f32x4*)(wr + 8), wd = *(const f32x4*)(wr + 12);\
                    _Pragma("unroll")                                                 \
                    for (int q = 0; q < 4; ++q) {                                     \
                        h1g[q]      = fmaf(xk, wa[q], h1g[q]);                        \
                        h1g[4 + q]  = fmaf(xk, wb[q], h1g[4 + q]);                    \
                        h1g[8 + q]  = fmaf(xk, wc[q], h1g[8 + q]);                    \
                        h1g[12 + q] = fmaf(xk, wd[q], h1g[12 + q]);                   \
                    }                                                                 \
                }
            L1K(xv0, 0)  L1K(xv1, 4)  L1K(xv2, 8)  L1K(xv3, 12)
            L1K(xv4, 16) L1K(xv5, 20) L1K(xv6, 24) L1K(xv7, 28)
            #undef L1K

            #pragma unroll
            for (int jj = 0; jj < 16; ++jj) h1g[jj] = fmaxf(h1g[jj], 0.f);

            // layer 2 partial: h2 += h1g . W2[jbase..jbase+15][:]
            #define L2B(H2, OFF)                                                      \
                {                                                                     \
                    f32x4 wa = *(const f32x4*)(wr + (OFF)),                           \
                          wb = *(const f32x4*)(wr + (OFF) + 4),                       \
                          wc = *(const f32x4*)(wr + (OFF) + 8),                       \
                          wd = *(const f32x4*)(wr + (OFF) + 12);                      \
                    _Pragma("unroll")                                                 \
                    for (int q = 0; q < 4; ++q) {                                     \
                        H2[q]      = fmaf(hj, wa[q], H2[q]);                          \
                        H2[4 + q]  = fmaf(hj, wb[q], H2[4 + q]);                      \
                        H2[8 + q]  = fmaf(hj, wc[q], H2[8 + q]);                      \
                        H2[12 + q] = fmaf(hj, wd[q], H2[12 + q]);                     \
                    }                                                                 \
                }
            #pragma unroll
            for (int jj = 0; jj < 16; ++jj) {
                float hj = h1g[jj];
                const float* wr = lw2 + (size_t)(jbase + jj) * N_LAT;
                L2B(h2_0, 0) L2B(h2_1, 16) L2B(h2_2, 32) L2B(h2_3, 48)
            }
            #undef L2B
        }

        // bias + relu + pool into the running event accumulator
        #define ACCB(ACC, H2, OFF)                                                    \
            {                                                                         \
                f32x4 ba = *(const f32x4*)(lb2 + (OFF)),                              \
                      bb = *(const f32x4*)(lb2 + (OFF) + 4),                          \
                      bc = *(const f32x4*)(lb2 + (OFF) + 8),                          \
                      bd = *(const f32x4*)(lb2 + (OFF) + 12);                         \
                _Pragma("unroll")                                                     \
                for (int q = 0; q < 4; ++q) {                                         \
                    ACC[q]      += fmaxf(H2[q]      + ba[q], 0.f);                    \
                    ACC[4 + q]  += fmaxf(H2[4 + q]  + bb[q], 0.f);                    \
                    ACC[8 + q]  += fmaxf(H2[8 + q]  + bc[q], 0.f);                    \
                    ACC[12 + q] += fmaxf(H2[12 + q] + bd[q], 0.f);                    \
                }                                                                     \
            }
        ACCB(acc0, h2_0, 0) ACCB(acc1, h2_1, 16) ACCB(acc2, h2_2, 32) ACCB(acc3, h2_3, 48)
        #undef ACCB
    }

    if (cur >= 0) {
        float* dst = pooled + (size_t)cur * N_LAT;
        #pragma unroll
        for (int mm = 0; mm < 16; ++mm) {
            atomicAdd(dst + mm,      acc0[mm]);
            atomicAdd(dst + 16 + mm, acc1[mm]);
            atomicAdd(dst + 32 + mm, acc2[mm]);
            atomicAdd(dst + 48 + mm, acc3[mm]);
        }
    }
}

// ---------------------------------------------------------------------------
// Kernel 2: rho MLP per event + sigmoid. One thread per event.
// Same LDS-weight treatment (66.5 KB: W1 33.3 KB + W2 33 KB + w3/b3).
// ---------------------------------------------------------------------------
__global__ __launch_bounds__(256, 2) void rho_kernel(
    const float* __restrict__ pooled,
    const float* __restrict__ w1, const float* __restrict__ b1,
    const float* __restrict__ w2, const float* __restrict__ b2,
    const float* __restrict__ w3, const float* __restrict__ b3,
    float* __restrict__ out, int n_events)
{
    __shared__ float lw1[N_LAT * R_HID + R_HID];   // w1 (8192) + b1 (128)
    __shared__ float lw2[R_HID * N_LAT + N_LAT];   // w2 (8192) + b2 (64)
    __shared__ float lw3[N_LAT];
    {
        int tid = threadIdx.x;
        for (int i = tid; i < N_LAT * R_HID; i += 256) lw1[i] = w1[i];
        for (int i = tid; i < R_HID * N_LAT; i += 256) lw2[i] = w2[i];
        if (tid < R_HID) lw1[N_LAT * R_HID + tid] = b1[tid];
        if (tid < N_LAT) lw2[R_HID * N_LAT + tid] = b2[tid];
        if (tid < N_LAT) lw3[tid] = w3[tid];
    }
    __syncthreads();
    const float* lb1 = lw1 + N_LAT * R_HID;
    const float* lb2 = lw2 + R_HID * N_LAT;

    int e = blockIdx.x * blockDim.x + threadIdx.x;
    if (e >= n_events) return;

    const f32x16* pp = reinterpret_cast<const f32x16*>(pooled + (size_t)e * N_LAT);
    f32x16 pv0 = pp[0], pv1 = pp[1], pv2 = pp[2], pv3 = pp[3];

    f32x16 r2_0, r2_1, r2_2, r2_3;   // pre-bias layer-2 accumulator (64)
    #pragma unroll
    for (int i = 0; i < 16; ++i) { r2_0[i] = 0.f; r2_1[i] = 0.f; r2_2[i] = 0.f; r2_3[i] = 0.f; }

    #pragma unroll 1
    for (int g = 0; g < 8; ++g) {
        const int jbase = g * 16;
        f32x16 r1g;
        {
            const float* lbg = lb1 + jbase;
            f32x4 ba = *(const f32x4*)(lbg),     bb = *(const f32x4*)(lbg + 4),
                  bc = *(const f32x4*)(lbg + 8), bd = *(const f32x4*)(lbg + 12);
            #pragma unroll
            for (int q = 0; q < 4; ++q) {
                r1g[q] = ba[q]; r1g[4+q] = bb[q]; r1g[8+q] = bc[q]; r1g[12+q] = bd[q];
            }
        }

        #define RL1(PV, KBASE)                                                        \
            _Pragma("unroll")                                                         \
            for (int kk = 0; kk < 16; ++kk) {                                         \
                float xk = (PV)[kk];                                                  \
                const float* wr = lw1 + (size_t)((KBASE) + kk) * R_HID + jbase;       \
                f32x4 wa = *(const f32x4*)(wr),     wb = *(const f32x4*)(wr + 4),     \
                      wc = *(const f32x4*)(wr + 8), wd = *(const f32x4*)(wr + 12);    \
                _Pragma("unroll")                                                     \
                for (int q = 0; q < 4; ++q) {                                         \
                    r1g[q]      = fmaf(xk, wa[q], r1g[q]);                            \
                    r1g[4 + q]  = fmaf(xk, wb[q], r1g[4 + q]);                        \
                    r1g[8 + q]  = fmaf(xk, wc[q], r1g[8 + q]);                        \
                    r1g[12 + q] = fmaf(xk, wd[q], r1g[12 + q]);                       \
                }                                                                     \
            }
        RL1(pv0, 0) RL1(pv1, 16) RL1(pv2, 32) RL1(pv3, 48)
        #undef RL1

        #pragma unroll
        for (int jj = 0; jj < 16; ++jj) r1g[jj] = fmaxf(r1g[jj], 0.f);

        #define RL2(R2, OFF)                                                          \
            {                                                                         \
                f32x4 wa = *(const f32x4*)(wr + (OFF)),                               \
                      wb = *(const f32x4*)(wr + (OFF) + 4),                           \
                      wc = *(const f32x4*)(wr + (OFF) + 8),                           \
                      wd = *(const f32x4*)(wr + (OFF) + 12);                          \
                _Pragma("unroll")                                                     \
                for (int q = 0; q < 4; ++q) {                                         \
                    R2[q]      = fmaf(rj, wa[q], R2[q]);                              \
                    R2[4 + q]  = fmaf(rj, wb[q], R2[4 + q]);                          \
                    R2[8 + q]  = fmaf(rj, wc[q], R2[8 + q]);                          \
                    R2[12 + q] = fmaf(rj, wd[q], R2[12 + q]);                         \
                }                                                                     \
            }
        #pragma unroll
        for (int jj = 0; jj < 16; ++jj) {
            float rj = r1g[jj];
            const float* wr = lw2 + (size_t)(jbase + jj) * N_LAT;
            RL2(r2_0, 0) RL2(r2_1, 16) RL2(r2_2, 32) RL2(r2_3, 48)
        }
        #undef RL2
    }

    // bias + relu + dot with w3 + sigmoid
    float z = b3[0];
    #pragma unroll
    for (int mm = 0; mm < 16; ++mm) {
        z += fmaxf(r2_0[mm] + lb2[mm],      0.f) * lw3[mm];
        z += fmaxf(r2_1[mm] + lb2[16 + mm], 0.f) * lw3[16 + mm];
        z += fmaxf(r2_2[mm] + lb2[32 + mm], 0.f) * lw3[32 + mm];
        z += fmaxf(r2_3[mm] + lb2[48 + mm], 0.f) * lw3[48 + mm];
    }
    out[e] = 1.f / (1.f + expf(-z));
}

extern "C" void kernel_launch(void* const* d_in, const int* in_sizes, int n_in,
                              void* d_out, int out_size, void* d_ws, size_t ws_size,
                              hipStream_t stream) {
    const float* x      = (const float*)d_in[0];
    const int*   eids   = (const int*)  d_in[1];
    const float* phi_w1 = (const float*)d_in[2];
    const float* phi_b1 = (const float*)d_in[3];
    const float* phi_w2 = (const float*)d_in[4];
    const float* phi_b2 = (const float*)d_in[5];
    const float* rho_w1 = (const float*)d_in[6];
    const float* rho_b1 = (const float*)d_in[7];
    const float* rho_w2 = (const float*)d_in[8];
    const float* rho_b2 = (const float*)d_in[9];
    const float* rho_w3 = (const float*)d_in[10];
    const float* rho_b3 = (const float*)d_in[11];
    float* out = (float*)d_out;

    int n_tracks = in_sizes[1];
    int n_events = out_size;

    float* pooled = (float*)d_ws;  // [n_events, 64] accumulator
    hipMemsetAsync(pooled, 0, (size_t)n_events * N_LAT * sizeof(float), stream);

    int n_threads = (n_tracks + TPT - 1) / TPT;
    int n_blocks  = (n_threads + 255) / 256;
    phi_pool_kernel<<<n_blocks, 256, 0, stream>>>(
        x, eids, phi_w1, phi_b1, phi_w2, phi_b2, pooled, n_tracks);

    int r_blocks = (n_events + 255) / 256;
    rho_kernel<<<r_blocks, 256, 0, stream>>>(
        pooled, rho_w1, rho_b1, rho_w2, rho_b2, rho_w3, rho_b3, out, n_events);
}

// Round 5
// 689.314 us; speedup vs baseline: 5.4795x; 5.4795x over previous
//
#include <hip/hip_runtime.h>
#include <hip/hip_bf16.h>
#include <math.h>

#define N_FEAT 32
#define N_HID  64   // 2*N_FEAT
#define N_LAT  64
#define R_HID  128  // 2*N_LAT
#define TPW    64   // tracks per wave-chunk

typedef float f32x16 __attribute__((ext_vector_type(16)));

__device__ __forceinline__ float rdlane(float v, int l) {
    return __int_as_float(__builtin_amdgcn_readlane(__float_as_int(v), l));
}

// ---------------------------------------------------------------------------
// phi + pooling, wave-parallel over features: lane j owns output feature j.
// Weights held in per-lane VGPRs (lane j: W1[:,j] 32 regs + W2[:,j] 64 regs),
// track data broadcast via v_readlane -> SGPR operand of v_fmac.
// Per-lane state is scalar (h1,h2,acc = 1 reg each) -> no spill (rounds 1-4:
// any 64-wide per-thread layer state spilled regardless of spelling).
// Flush = ONE coalesced global_atomic_add per event boundary.
// ---------------------------------------------------------------------------
#define W1C(K) ((K) < 16 ? w1a[(K)] : w1b[(K) - 16])
#define W2C(K) ((K) < 16 ? w2a[(K)] : (K) < 32 ? w2b[(K) - 16] : (K) < 48 ? w2c[(K) - 32] : w2d[(K) - 48])

template <int LOFF>
__device__ __forceinline__ void phi_track(
    int tidx, int eidv, float xv, int lane,
    const f32x16& w1a, const f32x16& w1b,
    const f32x16& w2a, const f32x16& w2b, const f32x16& w2c, const f32x16& w2d,
    float b1v, float b2v, int& cur, float& accv, float* __restrict__ pooled)
{
    int id = __builtin_amdgcn_readlane(eidv, tidx);   // uniform (SGPR-indexed)
    if (id != cur) {                                  // wave-uniform branch
        if (cur >= 0) atomicAdd(pooled + (size_t)cur * N_LAT + lane, accv);
        accv = 0.f;
        cur = id;
    }
    // layer 1: h1[lane] = relu(b1[lane] + sum_k x_k * W1[k][lane]); 4 chains
    float h1a = b1v, h1b = 0.f, h1c = 0.f, h1d = 0.f;
    #pragma unroll
    for (int k = 0; k < 32; k += 4) {
        h1a = fmaf(rdlane(xv, LOFF + k),     W1C(k),     h1a);
        h1b = fmaf(rdlane(xv, LOFF + k + 1), W1C(k + 1), h1b);
        h1c = fmaf(rdlane(xv, LOFF + k + 2), W1C(k + 2), h1c);
        h1d = fmaf(rdlane(xv, LOFF + k + 3), W1C(k + 3), h1d);
    }
    float h1 = fmaxf((h1a + h1b) + (h1c + h1d), 0.f);
    // layer 2: h2[lane] = relu(b2[lane] + sum_k h1_k * W2[k][lane]); 4 chains
    float h2a = b2v, h2b = 0.f, h2c = 0.f, h2d = 0.f;
    #pragma unroll
    for (int k = 0; k < 64; k += 4) {
        h2a = fmaf(rdlane(h1, k),     W2C(k),     h2a);
        h2b = fmaf(rdlane(h1, k + 1), W2C(k + 1), h2b);
        h2c = fmaf(rdlane(h1, k + 2), W2C(k + 2), h2c);
        h2d = fmaf(rdlane(h1, k + 3), W2C(k + 3), h2d);
    }
    accv += fmaxf((h2a + h2b) + (h2c + h2d), 0.f);
}

__global__ __launch_bounds__(256, 3) void phi_pool_kernel(
    const float* __restrict__ x,
    const int*   __restrict__ eids,
    const float* __restrict__ w1, const float* __restrict__ b1,
    const float* __restrict__ w2, const float* __restrict__ b2,
    float* __restrict__ pooled, int n_tracks)
{
    const int lane = threadIdx.x & 63;
    const long long gwave = (long long)blockIdx.x * 4 + (threadIdx.x >> 6);
    const long long base = gwave * TPW;
    if (base >= n_tracks) return;

    // per-lane weight columns: lane j holds W1[:,j] and W2[:,j]
    f32x16 w1a, w1b, w2a, w2b, w2c, w2d;
    #pragma unroll
    for (int k = 0; k < 16; ++k) {
        w1a[k] = w1[(k)      * N_HID + lane];
        w1b[k] = w1[(16 + k) * N_HID + lane];
        w2a[k] = w2[(k)      * N_LAT + lane];
        w2b[k] = w2[(16 + k) * N_LAT + lane];
        w2c[k] = w2[(32 + k) * N_LAT + lane];
        w2d[k] = w2[(48 + k) * N_LAT + lane];
    }
    const float b1v = b1[lane];
    const float b2v = b2[lane];

    // event-id chunk: lane l holds eids[base + l]
    long long ei = base + lane;
    if (ei >= n_tracks) ei = n_tracks - 1;
    int eidv = eids[ei];

    float accv = 0.f;
    int cur = -1;

    // x pair prefetch: lane l holds x[(pair tracks)*32 + l] (2 rows = 256 B)
    float xv = x[base * N_FEAT + lane];

    #pragma unroll 1
    for (int p = 0; p < TPW / 2; ++p) {
        float xnext = 0.f;
        long long npair = base + 2 * (p + 1);
        if (p + 1 < TPW / 2 && npair < n_tracks)
            xnext = x[npair * N_FEAT + lane];

        if (base + 2 * p < n_tracks)
            phi_track<0>(2 * p, eidv, xv, lane, w1a, w1b, w2a, w2b, w2c, w2d,
                         b1v, b2v, cur, accv, pooled);
        if (base + 2 * p + 1 < n_tracks)
            phi_track<32>(2 * p + 1, eidv, xv, lane, w1a, w1b, w2a, w2b, w2c, w2d,
                          b1v, b2v, cur, accv, pooled);
        xv = xnext;
    }
    if (cur >= 0) atomicAdd(pooled + (size_t)cur * N_LAT + lane, accv);
}

// ---------------------------------------------------------------------------
// rho, wave-parallel: one wave handles 8 events; lane j owns output j (and
// j+64 for layer 1). Weights broadcast from LDS (lane-contiguous ds_read,
// conflict-free); pooled-row elements broadcast via readlane (SGPR-indexed).
// Per-lane state: 8+16+8 scalars -> ~55 VGPR, no spill.
// ---------------------------------------------------------------------------
__global__ __launch_bounds__(256) void rho_kernel(
    const float* __restrict__ pooled,
    const float* __restrict__ w1, const float* __restrict__ b1,
    const float* __restrict__ w2, const float* __restrict__ b2,
    const float* __restrict__ w3, const float* __restrict__ b3,
    float* __restrict__ out, int n_events)
{
    __shared__ float lw1[N_LAT * R_HID];    // [64][128]
    __shared__ float lw2[R_HID * N_LAT];    // [128][64]
    __shared__ float lbias[R_HID + N_LAT + N_LAT + 1];
    {
        int tid = threadIdx.x;
        for (int i = tid; i < N_LAT * R_HID; i += 256) lw1[i] = w1[i];
        for (int i = tid; i < R_HID * N_LAT; i += 256) lw2[i] = w2[i];
        if (tid < R_HID) lbias[tid] = b1[tid];
        if (tid < N_LAT) lbias[R_HID + tid] = b2[tid];
        if (tid < N_LAT) lbias[R_HID + N_LAT + tid] = w3[tid];
        if (tid == 0)    lbias[R_HID + 2 * N_LAT] = b3[0];
    }
    __syncthreads();

    const int lane = threadIdx.x & 63;
    const long long ebase = ((long long)blockIdx.x * 4 + (threadIdx.x >> 6)) * 8;
    if (ebase >= n_events) return;

    const float b1va = lbias[lane];
    const float b1vb = lbias[64 + lane];
    const float b2v  = lbias[R_HID + lane];
    const float w3v  = lbias[R_HID + N_LAT + lane];
    const float b3v  = lbias[R_HID + 2 * N_LAT];

    float pe[8];
    #pragma unroll
    for (int i = 0; i < 8; ++i) {
        long long e = ebase + i;
        pe[i] = (e < n_events) ? pooled[e * N_LAT + lane] : 0.f;
    }

    // layer 1: r1a[i] = out j=lane, r1b[i] = out j=64+lane
    float r1a[8], r1b[8];
    #pragma unroll
    for (int i = 0; i < 8; ++i) { r1a[i] = b1va; r1b[i] = b1vb; }
    #pragma unroll 2
    for (int k = 0; k < N_LAT; ++k) {
        float wA = lw1[k * R_HID + lane];
        float wB = lw1[k * R_HID + 64 + lane];
        #pragma unroll
        for (int i = 0; i < 8; ++i) {
            float s = rdlane(pe[i], k);
            r1a[i] = fmaf(s, wA, r1a[i]);
            r1b[i] = fmaf(s, wB, r1b[i]);
        }
    }
    #pragma unroll
    for (int i = 0; i < 8; ++i) {
        r1a[i] = fmaxf(r1a[i], 0.f);
        r1b[i] = fmaxf(r1b[i], 0.f);
    }

    // layer 2: r2[i] = out j=lane
    float r2[8];
    #pragma unroll
    for (int i = 0; i < 8; ++i) r2[i] = b2v;
    #pragma unroll 2
    for (int k = 0; k < 64; ++k) {
        float w = lw2[k * N_LAT + lane];
        #pragma unroll
        for (int i = 0; i < 8; ++i) r2[i] = fmaf(rdlane(r1a[i], k), w, r2[i]);
    }
    #pragma unroll 2
    for (int k = 0; k < 64; ++k) {
        float w = lw2[(64 + k) * N_LAT + lane];
        #pragma unroll
        for (int i = 0; i < 8; ++i) r2[i] = fmaf(rdlane(r1b[i], k), w, r2[i]);
    }

    // layer 3 + sigmoid: wave-reduce relu(r2)*w3
    float zv = 0.f;
    #pragma unroll
    for (int i = 0; i < 8; ++i) {
        float t = fmaxf(r2[i], 0.f) * w3v;
        #pragma unroll
        for (int off = 32; off >= 1; off >>= 1) t += __shfl_xor(t, off, 64);
        zv = (lane == i) ? t : zv;
    }
    if (lane < 8 && ebase + lane < n_events)
        out[ebase + lane] = 1.f / (1.f + expf(-(zv + b3v)));
}

extern "C" void kernel_launch(void* const* d_in, const int* in_sizes, int n_in,
                              void* d_out, int out_size, void* d_ws, size_t ws_size,
                              hipStream_t stream) {
    const float* x      = (const float*)d_in[0];
    const int*   eids   = (const int*)  d_in[1];
    const float* phi_w1 = (const float*)d_in[2];
    const float* phi_b1 = (const float*)d_in[3];
    const float* phi_w2 = (const float*)d_in[4];
    const float* phi_b2 = (const float*)d_in[5];
    const float* rho_w1 = (const float*)d_in[6];
    const float* rho_b1 = (const float*)d_in[7];
    const float* rho_w2 = (const float*)d_in[8];
    const float* rho_b2 = (const float*)d_in[9];
    const float* rho_w3 = (const float*)d_in[10];
    const float* rho_b3 = (const float*)d_in[11];
    float* out = (float*)d_out;

    int n_tracks = in_sizes[1];
    int n_events = out_size;

    float* pooled = (float*)d_ws;  // [n_events, 64] accumulator
    hipMemsetAsync(pooled, 0, (size_t)n_events * N_LAT * sizeof(float), stream);

    long long waves = ((long long)n_tracks + TPW - 1) / TPW;
    int phi_blocks = (int)((waves + 3) / 4);
    phi_pool_kernel<<<phi_blocks, 256, 0, stream>>>(
        x, eids, phi_w1, phi_b1, phi_w2, phi_b2, pooled, n_tracks);

    long long ewaves = ((long long)n_events + 7) / 8;
    int rho_blocks = (int)((ewaves + 3) / 4);
    rho_kernel<<<rho_blocks, 256, 0, stream>>>(
        pooled, rho_w1, rho_b1, rho_w2, rho_b2, rho_w3, rho_b3, out, n_events);
}

// Round 6
// 526.357 us; speedup vs baseline: 7.1759x; 1.3096x over previous
//
#include <hip/hip_runtime.h>
#include <hip/hip_bf16.h>
#include <math.h>

#define N_FEAT 32
#define N_HID  64   // 2*N_FEAT
#define N_LAT  64
#define R_HID  128  // 2*N_LAT
#define TILES_PER_WAVE 32   // 512 tracks per wave
#define LDSW 68             // padded f32 row stride for h1 tile (2-way conflicts only)

typedef short s16x8 __attribute__((ext_vector_type(8)));
typedef float f32x4 __attribute__((ext_vector_type(4)));
typedef int   i32x4 __attribute__((ext_vector_type(4)));

__device__ __forceinline__ short bfs(float f) {          // f32 -> bf16 bits (RNE)
    __bf16 b = (__bf16)f;
    return __builtin_bit_cast(short, b);
}
__device__ __forceinline__ float bff(short s) {          // bf16 bits -> f32 (exact)
    return (float)__builtin_bit_cast(__bf16, s);
}
__device__ __forceinline__ f32x4 mfma16(s16x8 a, s16x8 b, f32x4 c) {
    return __builtin_amdgcn_mfma_f32_16x16x32_bf16(a, b, c, 0, 0, 0);
}
__device__ __forceinline__ float rdlane(float v, int l) {
    return __int_as_float(__builtin_amdgcn_readlane(__float_as_int(v), l));
}

// B-frag loader: lane (g,r), tile col c: b[j] = w[(k0+j)*64 + c], split hi/lo.
__device__ __forceinline__ void load_bfrag(const float* __restrict__ w, int k0, int c,
                                           s16x8& hi, s16x8& lo) {
    #pragma unroll
    for (int j = 0; j < 8; ++j) {
        float f = w[(size_t)(k0 + j) * 64 + c];
        short h = bfs(f);
        hi[j] = h;
        lo[j] = bfs(f - bff(h));
    }
}

// ---------------------------------------------------------------------------
// phi via bf16 MFMA with hi/lo split (fp32-accurate): per 16-track tile,
// layer1 = 12 MFMA, layer2 = 24 MFMA. h1 goes through a per-wave LDS tile
// (f32, [16][68]) to re-shape C-layout -> A-layout. Pooling: per-run f32
// atomics within each lane-group's 4-track window (wave-subgroup-uniform
// branches; sorted ids => runs are long, flushes rare).
// MFMA layouts (guide §3, m89/m91-verified C/D): A: row=l&15, k=8*(l>>4)+j;
// B: col=l&15, k=8*(l>>4)+j; C/D: col=l&15, row=4*(l>>4)+reg.
// ---------------------------------------------------------------------------
__global__ __launch_bounds__(256, 2) void phi_mfma_kernel(
    const float* __restrict__ x,
    const int*   __restrict__ eids,
    const float* __restrict__ w1, const float* __restrict__ b1,
    const float* __restrict__ w2, const float* __restrict__ b2,
    float* __restrict__ pooled, int n_tracks)
{
    __shared__ float h1lds[4][16 * LDSW];   // per-wave slice, no cross-wave sharing
    const int lane = threadIdx.x & 63;
    const int wv   = threadIdx.x >> 6;
    const int g    = lane >> 4;   // 0..3
    const int r    = lane & 15;   // 0..15
    float* lds = h1lds[wv];

    const long long wbase = ((long long)blockIdx.x * 4 + wv) * (16LL * TILES_PER_WAVE);
    if (wbase >= n_tracks) return;   // no barriers in this kernel -> safe

    // ---- loop-invariant weight fragments in VGPRs (96 regs) ----
    s16x8 w1h[4], w1l[4], w2h[2][4], w2l[2][4];
    #pragma unroll
    for (int n = 0; n < 4; ++n) load_bfrag(w1, 8 * g, r + 16 * n, w1h[n], w1l[n]);
    #pragma unroll
    for (int s = 0; s < 2; ++s)
        #pragma unroll
        for (int n = 0; n < 4; ++n)
            load_bfrag(w2, 32 * s + 8 * g, r + 16 * n, w2h[s][n], w2l[s][n]);

    float b1v[4], b2v[4];
    #pragma unroll
    for (int n = 0; n < 4; ++n) { b1v[n] = b1[r + 16 * n]; b2v[n] = b2[r + 16 * n]; }

    // ---- prologue loads for tile 0 ----
    long long row0 = wbase + r; if (row0 > n_tracks - 1) row0 = n_tracks - 1;
    f32x4 xa = *(const f32x4*)(x + row0 * N_FEAT + 8 * g);
    f32x4 xb = *(const f32x4*)(x + row0 * N_FEAT + 8 * g + 4);
    long long ib0 = wbase + 4 * g; if (ib0 > n_tracks - 4) ib0 = (n_tracks - 4) & ~3LL;
    i32x4 e4 = *(const i32x4*)(eids + ib0);

    #pragma unroll 1
    for (int t = 0; t < TILES_PER_WAVE; ++t) {
        long long tb = wbase + 16LL * t;
        if (tb >= n_tracks) break;

        // ---- convert current x to hi/lo A-frags ----
        s16x8 xh, xl;
        #pragma unroll
        for (int j = 0; j < 4; ++j) {
            short h0 = bfs(xa[j]); xh[j] = h0;     xl[j] = bfs(xa[j] - bff(h0));
            short h1 = bfs(xb[j]); xh[4 + j] = h1; xl[4 + j] = bfs(xb[j] - bff(h1));
        }

        // ---- prefetch tile t+1 (hides HBM latency under MFMA work) ----
        f32x4 xa2, xb2; i32x4 e42;
        const bool pf = (t + 1 < TILES_PER_WAVE) && (tb + 16 < n_tracks);
        if (pf) {
            long long rowp = tb + 16 + r; if (rowp > n_tracks - 1) rowp = n_tracks - 1;
            xa2 = *(const f32x4*)(x + rowp * N_FEAT + 8 * g);
            xb2 = *(const f32x4*)(x + rowp * N_FEAT + 8 * g + 4);
            long long ibp = tb + 16 + 4 * g; if (ibp > n_tracks - 4) ibp = (n_tracks - 4) & ~3LL;
            e42 = *(const i32x4*)(eids + ibp);
        }

        // ---- layer 1: h1C[n] = x @ W1 tile n (split: 3 MFMA each) ----
        f32x4 h1C[4];
        #pragma unroll
        for (int n = 0; n < 4; ++n) {
            f32x4 c = {0.f, 0.f, 0.f, 0.f};
            c = mfma16(xl, w1h[n], c);
            c = mfma16(xh, w1l[n], c);
            c = mfma16(xh, w1h[n], c);
            h1C[n] = c;
        }

        // ---- bias+relu, stage h1 to LDS (f32, [track][feat], stride 68) ----
        #pragma unroll
        for (int n = 0; n < 4; ++n) {
            #pragma unroll
            for (int q = 0; q < 4; ++q) {
                float f = fmaxf(h1C[n][q] + b1v[n], 0.f);
                lds[(4 * g + q) * LDSW + r + 16 * n] = f;
            }
        }

        // ---- layer 2: read h1 A-frags back (k-contiguous), split, 24 MFMA ----
        f32x4 h2C[4] = {{0.f,0.f,0.f,0.f},{0.f,0.f,0.f,0.f},{0.f,0.f,0.f,0.f},{0.f,0.f,0.f,0.f}};
        #pragma unroll
        for (int s = 0; s < 2; ++s) {
            f32x4 av = *(const f32x4*)&lds[r * LDSW + 32 * s + 8 * g];
            f32x4 bv = *(const f32x4*)&lds[r * LDSW + 32 * s + 8 * g + 4];
            s16x8 ah, al;
            #pragma unroll
            for (int j = 0; j < 4; ++j) {
                short h0 = bfs(av[j]); ah[j] = h0;     al[j] = bfs(av[j] - bff(h0));
                short h1 = bfs(bv[j]); ah[4 + j] = h1; al[4 + j] = bfs(bv[j] - bff(h1));
            }
            #pragma unroll
            for (int n = 0; n < 4; ++n) {
                h2C[n] = mfma16(al, w2h[s][n], h2C[n]);
                h2C[n] = mfma16(ah, w2l[s][n], h2C[n]);
                h2C[n] = mfma16(ah, w2h[s][n], h2C[n]);
            }
        }

        // ---- bias+relu+pool: per-run flush within this lane-group's 4 tracks ----
        const int rem = (int)((n_tracks - tb < 16) ? (n_tracks - tb) : 16);
        const bool c01 = (e4[1] == e4[0]), c12 = (e4[2] == e4[1]), c23 = (e4[3] == e4[2]);
        #pragma unroll
        for (int n = 0; n < 4; ++n) {
            f32x4 hv;
            #pragma unroll
            for (int q = 0; q < 4; ++q) {
                float f = fmaxf(h2C[n][q] + b2v[n], 0.f);
                hv[q] = (4 * g + q < rem) ? f : 0.f;
            }
            float* pp = pooled + (size_t)(r + 16 * n);
            float run = hv[0];
            if (c01) run += hv[1]; else { atomicAdd(pp + (size_t)e4[0] * N_LAT, run); run = hv[1]; }
            if (c12) run += hv[2]; else { atomicAdd(pp + (size_t)e4[1] * N_LAT, run); run = hv[2]; }
            if (c23) run += hv[3]; else { atomicAdd(pp + (size_t)e4[2] * N_LAT, run); run = hv[3]; }
            atomicAdd(pp + (size_t)e4[3] * N_LAT, run);
        }

        if (pf) { xa = xa2; xb = xb2; e4 = e42; }
    }
}

// ---------------------------------------------------------------------------
// rho, wave-parallel (unchanged from round 5): one wave = 8 events; lane j
// owns output j (and j+64 in layer 1); weights from LDS, broadcasts via
// readlane. ~55 VGPR, no spill. Stays f32 (pooled magnitudes too large for
// plain bf16; 38 us is not the bottleneck).
// ---------------------------------------------------------------------------
__global__ __launch_bounds__(256) void rho_kernel(
    const float* __restrict__ pooled,
    const float* __restrict__ w1, const float* __restrict__ b1,
    const float* __restrict__ w2, const float* __restrict__ b2,
    const float* __restrict__ w3, const float* __restrict__ b3,
    float* __restrict__ out, int n_events)
{
    __shared__ float lw1[N_LAT * R_HID];
    __shared__ float lw2[R_HID * N_LAT];
    __shared__ float lbias[R_HID + N_LAT + N_LAT + 1];
    {
        int tid = threadIdx.x;
        for (int i = tid; i < N_LAT * R_HID; i += 256) lw1[i] = w1[i];
        for (int i = tid; i < R_HID * N_LAT; i += 256) lw2[i] = w2[i];
        if (tid < R_HID) lbias[tid] = b1[tid];
        if (tid < N_LAT) lbias[R_HID + tid] = b2[tid];
        if (tid < N_LAT) lbias[R_HID + N_LAT + tid] = w3[tid];
        if (tid == 0)    lbias[R_HID + 2 * N_LAT] = b3[0];
    }
    __syncthreads();

    const int lane = threadIdx.x & 63;
    const long long ebase = ((long long)blockIdx.x * 4 + (threadIdx.x >> 6)) * 8;
    if (ebase >= n_events) return;

    const float b1va = lbias[lane];
    const float b1vb = lbias[64 + lane];
    const float b2v  = lbias[R_HID + lane];
    const float w3v  = lbias[R_HID + N_LAT + lane];
    const float b3v  = lbias[R_HID + 2 * N_LAT];

    float pe[8];
    #pragma unroll
    for (int i = 0; i < 8; ++i) {
        long long e = ebase + i;
        pe[i] = (e < n_events) ? pooled[e * N_LAT + lane] : 0.f;
    }

    float r1a[8], r1b[8];
    #pragma unroll
    for (int i = 0; i < 8; ++i) { r1a[i] = b1va; r1b[i] = b1vb; }
    #pragma unroll 2
    for (int k = 0; k < N_LAT; ++k) {
        float wA = lw1[k * R_HID + lane];
        float wB = lw1[k * R_HID + 64 + lane];
        #pragma unroll
        for (int i = 0; i < 8; ++i) {
            float s = rdlane(pe[i], k);
            r1a[i] = fmaf(s, wA, r1a[i]);
            r1b[i] = fmaf(s, wB, r1b[i]);
        }
    }
    #pragma unroll
    for (int i = 0; i < 8; ++i) {
        r1a[i] = fmaxf(r1a[i], 0.f);
        r1b[i] = fmaxf(r1b[i], 0.f);
    }

    float r2[8];
    #pragma unroll
    for (int i = 0; i < 8; ++i) r2[i] = b2v;
    #pragma unroll 2
    for (int k = 0; k < 64; ++k) {
        float w = lw2[k * N_LAT + lane];
        #pragma unroll
        for (int i = 0; i < 8; ++i) r2[i] = fmaf(rdlane(r1a[i], k), w, r2[i]);
    }
    #pragma unroll 2
    for (int k = 0; k < 64; ++k) {
        float w = lw2[(64 + k) * N_LAT + lane];
        #pragma unroll
        for (int i = 0; i < 8; ++i) r2[i] = fmaf(rdlane(r1b[i], k), w, r2[i]);
    }

    float zv = 0.f;
    #pragma unroll
    for (int i = 0; i < 8; ++i) {
        float tv = fmaxf(r2[i], 0.f) * w3v;
        #pragma unroll
        for (int off = 32; off >= 1; off >>= 1) tv += __shfl_xor(tv, off, 64);
        zv = (lane == i) ? tv : zv;
    }
    if (lane < 8 && ebase + lane < n_events)
        out[ebase + lane] = 1.f / (1.f + expf(-(zv + b3v)));
}

extern "C" void kernel_launch(void* const* d_in, const int* in_sizes, int n_in,
                              void* d_out, int out_size, void* d_ws, size_t ws_size,
                              hipStream_t stream) {
    const float* x      = (const float*)d_in[0];
    const int*   eids   = (const int*)  d_in[1];
    const float* phi_w1 = (const float*)d_in[2];
    const float* phi_b1 = (const float*)d_in[3];
    const float* phi_w2 = (const float*)d_in[4];
    const float* phi_b2 = (const float*)d_in[5];
    const float* rho_w1 = (const float*)d_in[6];
    const float* rho_b1 = (const float*)d_in[7];
    const float* rho_w2 = (const float*)d_in[8];
    const float* rho_b2 = (const float*)d_in[9];
    const float* rho_w3 = (const float*)d_in[10];
    const float* rho_b3 = (const float*)d_in[11];
    float* out = (float*)d_out;

    int n_tracks = in_sizes[1];
    int n_events = out_size;

    float* pooled = (float*)d_ws;  // [n_events, 64] accumulator
    hipMemsetAsync(pooled, 0, (size_t)n_events * N_LAT * sizeof(float), stream);

    long long tracks_per_wave = 16LL * TILES_PER_WAVE;
    long long waves  = ((long long)n_tracks + tracks_per_wave - 1) / tracks_per_wave;
    int phi_blocks   = (int)((waves + 3) / 4);
    phi_mfma_kernel<<<phi_blocks, 256, 0, stream>>>(
        x, eids, phi_w1, phi_b1, phi_w2, phi_b2, pooled, n_tracks);

    long long ewaves = ((long long)n_events + 7) / 8;
    int rho_blocks = (int)((ewaves + 3) / 4);
    rho_kernel<<<rho_blocks, 256, 0, stream>>>(
        pooled, rho_w1, rho_b1, rho_w2, rho_b2, rho_w3, rho_b3, out, n_events);
}

// Round 7
// 504.792 us; speedup vs baseline: 7.4825x; 1.0427x over previous
//
#include <hip/hip_runtime.h>
#include <hip/hip_bf16.h>
#include <math.h>

#define N_FEAT 32
#define N_HID  64   // 2*N_FEAT
#define N_LAT  64
#define R_HID  128  // 2*N_LAT
#define TILES_PER_WAVE 8    // 128 tracks per wave: 15625 waves total (round-6
                            // lesson: 32 tiles/wave -> only 3907 waves = 3.8/SIMD,
                            // stall-bound at MfmaUtil 7%/VALUBusy 13%)
#define LDSW 68             // padded f32 row stride for h1 tile (2-way conflicts only)

typedef short s16x8 __attribute__((ext_vector_type(8)));
typedef float f32x4 __attribute__((ext_vector_type(4)));
typedef int   i32x4 __attribute__((ext_vector_type(4)));

__device__ __forceinline__ short bfs(float f) {          // f32 -> bf16 bits (RNE)
    __bf16 b = (__bf16)f;
    return __builtin_bit_cast(short, b);
}
__device__ __forceinline__ float bff(short s) {          // bf16 bits -> f32 (exact)
    return (float)__builtin_bit_cast(__bf16, s);
}
__device__ __forceinline__ f32x4 mfma16(s16x8 a, s16x8 b, f32x4 c) {
    return __builtin_amdgcn_mfma_f32_16x16x32_bf16(a, b, c, 0, 0, 0);
}
__device__ __forceinline__ float rdlane(float v, int l) {
    return __int_as_float(__builtin_amdgcn_readlane(__float_as_int(v), l));
}

// B-frag loader: lane (g,r), tile col c: b[j] = w[(k0+j)*64 + c], split hi/lo.
__device__ __forceinline__ void load_bfrag(const float* __restrict__ w, int k0, int c,
                                           s16x8& hi, s16x8& lo) {
    #pragma unroll
    for (int j = 0; j < 8; ++j) {
        float f = w[(size_t)(k0 + j) * 64 + c];
        short h = bfs(f);
        hi[j] = h;
        lo[j] = bfs(f - bff(h));
    }
}

// ---------------------------------------------------------------------------
// phi via bf16 MFMA with hi/lo split (fp32-accurate): per 16-track tile,
// layer1 = 12 MFMA, layer2 = 24 MFMA. h1 goes through a per-wave LDS tile
// (f32, [16][68]) to re-shape C-layout -> A-layout. Pooling: per-run f32
// atomics within each lane-group's 4-track window.
// MFMA layouts (guide §3, m89/m91-verified C/D): A: row=l&15, k=8*(l>>4)+j;
// B: col=l&15, k=8*(l>>4)+j; C/D: col=l&15, row=4*(l>>4)+reg.
// ---------------------------------------------------------------------------
__global__ __launch_bounds__(256, 2) void phi_mfma_kernel(
    const float* __restrict__ x,
    const int*   __restrict__ eids,
    const float* __restrict__ w1, const float* __restrict__ b1,
    const float* __restrict__ w2, const float* __restrict__ b2,
    float* __restrict__ pooled, int n_tracks)
{
    __shared__ float h1lds[4][16 * LDSW];   // per-wave slice, no cross-wave sharing
    const int lane = threadIdx.x & 63;
    const int wv   = threadIdx.x >> 6;
    const int g    = lane >> 4;   // 0..3
    const int r    = lane & 15;   // 0..15
    float* lds = h1lds[wv];

    const long long wbase = ((long long)blockIdx.x * 4 + wv) * (16LL * TILES_PER_WAVE);
    if (wbase >= n_tracks) return;   // no barriers in this kernel -> safe

    // ---- loop-invariant weight fragments in VGPRs (96 regs) ----
    s16x8 w1h[4], w1l[4], w2h[2][4], w2l[2][4];
    #pragma unroll
    for (int n = 0; n < 4; ++n) load_bfrag(w1, 8 * g, r + 16 * n, w1h[n], w1l[n]);
    #pragma unroll
    for (int s = 0; s < 2; ++s)
        #pragma unroll
        for (int n = 0; n < 4; ++n)
            load_bfrag(w2, 32 * s + 8 * g, r + 16 * n, w2h[s][n], w2l[s][n]);

    float b1v[4], b2v[4];
    #pragma unroll
    for (int n = 0; n < 4; ++n) { b1v[n] = b1[r + 16 * n]; b2v[n] = b2[r + 16 * n]; }

    // ---- prologue loads for tile 0 ----
    long long row0 = wbase + r; if (row0 > n_tracks - 1) row0 = n_tracks - 1;
    f32x4 xa = *(const f32x4*)(x + row0 * N_FEAT + 8 * g);
    f32x4 xb = *(const f32x4*)(x + row0 * N_FEAT + 8 * g + 4);
    long long ib0 = wbase + 4 * g; if (ib0 > n_tracks - 4) ib0 = (n_tracks - 4) & ~3LL;
    i32x4 e4 = *(const i32x4*)(eids + ib0);

    #pragma unroll 1
    for (int t = 0; t < TILES_PER_WAVE; ++t) {
        long long tb = wbase + 16LL * t;
        if (tb >= n_tracks) break;

        // ---- convert current x to hi/lo A-frags ----
        s16x8 xh, xl;
        #pragma unroll
        for (int j = 0; j < 4; ++j) {
            short h0 = bfs(xa[j]); xh[j] = h0;     xl[j] = bfs(xa[j] - bff(h0));
            short h1 = bfs(xb[j]); xh[4 + j] = h1; xl[4 + j] = bfs(xb[j] - bff(h1));
        }

        // ---- prefetch tile t+1 (hides HBM latency under MFMA work) ----
        f32x4 xa2, xb2; i32x4 e42;
        const bool pf = (t + 1 < TILES_PER_WAVE) && (tb + 16 < n_tracks);
        if (pf) {
            long long rowp = tb + 16 + r; if (rowp > n_tracks - 1) rowp = n_tracks - 1;
            xa2 = *(const f32x4*)(x + rowp * N_FEAT + 8 * g);
            xb2 = *(const f32x4*)(x + rowp * N_FEAT + 8 * g + 4);
            long long ibp = tb + 16 + 4 * g; if (ibp > n_tracks - 4) ibp = (n_tracks - 4) & ~3LL;
            e42 = *(const i32x4*)(eids + ibp);
        }

        // ---- layer 1: h1C[n] = x @ W1 tile n (split: 3 MFMA each) ----
        f32x4 h1C[4];
        #pragma unroll
        for (int n = 0; n < 4; ++n) {
            f32x4 c = {0.f, 0.f, 0.f, 0.f};
            c = mfma16(xl, w1h[n], c);
            c = mfma16(xh, w1l[n], c);
            c = mfma16(xh, w1h[n], c);
            h1C[n] = c;
        }

        // ---- bias+relu, stage h1 to LDS (f32, [track][feat], stride 68) ----
        #pragma unroll
        for (int n = 0; n < 4; ++n) {
            #pragma unroll
            for (int q = 0; q < 4; ++q) {
                float f = fmaxf(h1C[n][q] + b1v[n], 0.f);
                lds[(4 * g + q) * LDSW + r + 16 * n] = f;
            }
        }

        // ---- layer 2: read h1 A-frags back (k-contiguous), split, 24 MFMA ----
        f32x4 h2C[4] = {{0.f,0.f,0.f,0.f},{0.f,0.f,0.f,0.f},{0.f,0.f,0.f,0.f},{0.f,0.f,0.f,0.f}};
        #pragma unroll
        for (int s = 0; s < 2; ++s) {
            f32x4 av = *(const f32x4*)&lds[r * LDSW + 32 * s + 8 * g];
            f32x4 bv = *(const f32x4*)&lds[r * LDSW + 32 * s + 8 * g + 4];
            s16x8 ah, al;
            #pragma unroll
            for (int j = 0; j < 4; ++j) {
                short h0 = bfs(av[j]); ah[j] = h0;     al[j] = bfs(av[j] - bff(h0));
                short h1 = bfs(bv[j]); ah[4 + j] = h1; al[4 + j] = bfs(bv[j] - bff(h1));
            }
            #pragma unroll
            for (int n = 0; n < 4; ++n) {
                h2C[n] = mfma16(al, w2h[s][n], h2C[n]);
                h2C[n] = mfma16(ah, w2l[s][n], h2C[n]);
                h2C[n] = mfma16(ah, w2h[s][n], h2C[n]);
            }
        }

        // ---- bias+relu+pool: per-run flush within this lane-group's 4 tracks ----
        const int rem = (int)((n_tracks - tb < 16) ? (n_tracks - tb) : 16);
        const bool c01 = (e4[1] == e4[0]), c12 = (e4[2] == e4[1]), c23 = (e4[3] == e4[2]);
        #pragma unroll
        for (int n = 0; n < 4; ++n) {
            f32x4 hv;
            #pragma unroll
            for (int q = 0; q < 4; ++q) {
                float f = fmaxf(h2C[n][q] + b2v[n], 0.f);
                hv[q] = (4 * g + q < rem) ? f : 0.f;
            }
            float* pp = pooled + (size_t)(r + 16 * n);
            float run = hv[0];
            if (c01) run += hv[1]; else { atomicAdd(pp + (size_t)e4[0] * N_LAT, run); run = hv[1]; }
            if (c12) run += hv[2]; else { atomicAdd(pp + (size_t)e4[1] * N_LAT, run); run = hv[2]; }
            if (c23) run += hv[3]; else { atomicAdd(pp + (size_t)e4[2] * N_LAT, run); run = hv[3]; }
            atomicAdd(pp + (size_t)e4[3] * N_LAT, run);
        }

        if (pf) { xa = xa2; xb = xb2; e4 = e42; }
    }
}

// ---------------------------------------------------------------------------
// rho, wave-parallel (unchanged): one wave = 8 events; lane j owns output j
// (and j+64 in layer 1); weights from LDS, broadcasts via readlane.
// ---------------------------------------------------------------------------
__global__ __launch_bounds__(256) void rho_kernel(
    const float* __restrict__ pooled,
    const float* __restrict__ w1, const float* __restrict__ b1,
    const float* __restrict__ w2, const float* __restrict__ b2,
    const float* __restrict__ w3, const float* __restrict__ b3,
    float* __restrict__ out, int n_events)
{
    __shared__ float lw1[N_LAT * R_HID];
    __shared__ float lw2[R_HID * N_LAT];
    __shared__ float lbias[R_HID + N_LAT + N_LAT + 1];
    {
        int tid = threadIdx.x;
        for (int i = tid; i < N_LAT * R_HID; i += 256) lw1[i] = w1[i];
        for (int i = tid; i < R_HID * N_LAT; i += 256) lw2[i] = w2[i];
        if (tid < R_HID) lbias[tid] = b1[tid];
        if (tid < N_LAT) lbias[R_HID + tid] = b2[tid];
        if (tid < N_LAT) lbias[R_HID + N_LAT + tid] = w3[tid];
        if (tid == 0)    lbias[R_HID + 2 * N_LAT] = b3[0];
    }
    __syncthreads();

    const int lane = threadIdx.x & 63;
    const long long ebase = ((long long)blockIdx.x * 4 + (threadIdx.x >> 6)) * 8;
    if (ebase >= n_events) return;

    const float b1va = lbias[lane];
    const float b1vb = lbias[64 + lane];
    const float b2v  = lbias[R_HID + lane];
    const float w3v  = lbias[R_HID + N_LAT + lane];
    const float b3v  = lbias[R_HID + 2 * N_LAT];

    float pe[8];
    #pragma unroll
    for (int i = 0; i < 8; ++i) {
        long long e = ebase + i;
        pe[i] = (e < n_events) ? pooled[e * N_LAT + lane] : 0.f;
    }

    float r1a[8], r1b[8];
    #pragma unroll
    for (int i = 0; i < 8; ++i) { r1a[i] = b1va; r1b[i] = b1vb; }
    #pragma unroll 2
    for (int k = 0; k < N_LAT; ++k) {
        float wA = lw1[k * R_HID + lane];
        float wB = lw1[k * R_HID + 64 + lane];
        #pragma unroll
        for (int i = 0; i < 8; ++i) {
            float s = rdlane(pe[i], k);
            r1a[i] = fmaf(s, wA, r1a[i]);
            r1b[i] = fmaf(s, wB, r1b[i]);
        }
    }
    #pragma unroll
    for (int i = 0; i < 8; ++i) {
        r1a[i] = fmaxf(r1a[i], 0.f);
        r1b[i] = fmaxf(r1b[i], 0.f);
    }

    float r2[8];
    #pragma unroll
    for (int i = 0; i < 8; ++i) r2[i] = b2v;
    #pragma unroll 2
    for (int k = 0; k < 64; ++k) {
        float w = lw2[k * N_LAT + lane];
        #pragma unroll
        for (int i = 0; i < 8; ++i) r2[i] = fmaf(rdlane(r1a[i], k), w, r2[i]);
    }
    #pragma unroll 2
    for (int k = 0; k < 64; ++k) {
        float w = lw2[(64 + k) * N_LAT + lane];
        #pragma unroll
        for (int i = 0; i < 8; ++i) r2[i] = fmaf(rdlane(r1b[i], k), w, r2[i]);
    }

    float zv = 0.f;
    #pragma unroll
    for (int i = 0; i < 8; ++i) {
        float tv = fmaxf(r2[i], 0.f) * w3v;
        #pragma unroll
        for (int off = 32; off >= 1; off >>= 1) tv += __shfl_xor(tv, off, 64);
        zv = (lane == i) ? tv : zv;
    }
    if (lane < 8 && ebase + lane < n_events)
        out[ebase + lane] = 1.f / (1.f + expf(-(zv + b3v)));
}

extern "C" void kernel_launch(void* const* d_in, const int* in_sizes, int n_in,
                              void* d_out, int out_size, void* d_ws, size_t ws_size,
                              hipStream_t stream) {
    const float* x      = (const float*)d_in[0];
    const int*   eids   = (const int*)  d_in[1];
    const float* phi_w1 = (const float*)d_in[2];
    const float* phi_b1 = (const float*)d_in[3];
    const float* phi_w2 = (const float*)d_in[4];
    const float* phi_b2 = (const float*)d_in[5];
    const float* rho_w1 = (const float*)d_in[6];
    const float* rho_b1 = (const float*)d_in[7];
    const float* rho_w2 = (const float*)d_in[8];
    const float* rho_b2 = (const float*)d_in[9];
    const float* rho_w3 = (const float*)d_in[10];
    const float* rho_b3 = (const float*)d_in[11];
    float* out = (float*)d_out;

    int n_tracks = in_sizes[1];
    int n_events = out_size;

    float* pooled = (float*)d_ws;  // [n_events, 64] accumulator
    hipMemsetAsync(pooled, 0, (size_t)n_events * N_LAT * sizeof(float), stream);

    long long tracks_per_wave = 16LL * TILES_PER_WAVE;
    long long waves  = ((long long)n_tracks + tracks_per_wave - 1) / tracks_per_wave;
    int phi_blocks   = (int)((waves + 3) / 4);
    phi_mfma_kernel<<<phi_blocks, 256, 0, stream>>>(
        x, eids, phi_w1, phi_b1, phi_w2, phi_b2, pooled, n_tracks);

    long long ewaves = ((long long)n_events + 7) / 8;
    int rho_blocks = (int)((ewaves + 3) / 4);
    rho_kernel<<<rho_blocks, 256, 0, stream>>>(
        pooled, rho_w1, rho_b1, rho_w2, rho_b2, rho_w3, rho_b3, out, n_events);
}

// Round 8
// 380.352 us; speedup vs baseline: 9.9305x; 1.3272x over previous
//
#include <hip/hip_runtime.h>
#include <hip/hip_bf16.h>
#include <math.h>

#define N_FEAT 32
#define N_HID  64   // 2*N_FEAT
#define N_LAT  64
#define R_HID  128  // 2*N_LAT
#define TILES_PER_WAVE 8    // 128 tracks/wave -> 15625 waves
#define LDSW 68             // padded f32 row stride for h1 tile (2-way conflicts only)

typedef short s16x8 __attribute__((ext_vector_type(8)));
typedef float f32x4 __attribute__((ext_vector_type(4)));
typedef int   i32x4 __attribute__((ext_vector_type(4)));

__device__ __forceinline__ short bfs(float f) {          // f32 -> bf16 bits (RNE)
    __bf16 b = (__bf16)f;
    return __builtin_bit_cast(short, b);
}
__device__ __forceinline__ float bff(short s) {          // bf16 bits -> f32 (exact)
    return (float)__builtin_bit_cast(__bf16, s);
}
__device__ __forceinline__ f32x4 mfma16(s16x8 a, s16x8 b, f32x4 c) {
    return __builtin_amdgcn_mfma_f32_16x16x32_bf16(a, b, c, 0, 0, 0);
}
__device__ __forceinline__ float rdlane(float v, int l) {
    return __int_as_float(__builtin_amdgcn_readlane(__float_as_int(v), l));
}

// B-frag loader: lane (g,r), tile col c: b[j] = w[(k0+j)*64 + c], split hi/lo.
__device__ __forceinline__ void load_bfrag(const float* __restrict__ w, int k0, int c,
                                           s16x8& hi, s16x8& lo) {
    #pragma unroll
    for (int j = 0; j < 8; ++j) {
        float f = w[(size_t)(k0 + j) * 64 + c];
        short h = bfs(f);
        hi[j] = h;
        lo[j] = bfs(f - bff(h));
    }
}

// ---------------------------------------------------------------------------
// phi via bf16 MFMA, hi/lo split (unchanged math, absmax-verified 0.0039).
// Round-7 lesson: 24 weight frags in regs -> ~190 unified VGPR/AGPR -> 2
// waves/SIMD residency cap -> MfmaUtil 7%. Fix: W2 frags pre-packed in LDS
// (16 KB, per-lane 16B units, full-BW ds_read_b128); W1 stays in VGPRs.
// __launch_bounds__(256,4) caps regs at 128 -> 4 waves/SIMD; LDS 33.8 KB ->
// 4 blocks/CU. Pooling carries runs across tiles (flush on id change only).
// ---------------------------------------------------------------------------
__global__ __launch_bounds__(256, 4) void phi_mfma_kernel(
    const float* __restrict__ x,
    const int*   __restrict__ eids,
    const float* __restrict__ w1, const float* __restrict__ b1,
    const float* __restrict__ w2, const float* __restrict__ b2,
    float* __restrict__ pooled, int n_tracks)
{
    __shared__ s16x8 wfrag[16][64];         // W2 frags: f = s*4+n (hi), 8+s*4+n (lo)
    __shared__ float h1lds[4][16 * LDSW];   // per-wave h1 staging

    const int lane = threadIdx.x & 63;
    const int wv   = threadIdx.x >> 6;
    const int g    = lane >> 4;   // 0..3
    const int r    = lane & 15;   // 0..15

    // ---- one-time cooperative pack of W2 frags (wave wv packs f=wv,wv+4,..) ----
    #pragma unroll
    for (int ff = 0; ff < 4; ++ff) {
        int f   = wv + 4 * ff;
        int idx = f & 7;
        int s   = idx >> 2;
        int n   = idx & 3;
        bool lo = (f >= 8);
        s16x8 v;
        #pragma unroll
        for (int j = 0; j < 8; ++j) {
            float fv = w2[(size_t)(32 * s + 8 * g + j) * 64 + (r + 16 * n)];
            short h  = bfs(fv);
            v[j] = lo ? bfs(fv - bff(h)) : h;
        }
        wfrag[f][lane] = v;
    }
    __syncthreads();

    float* lds = h1lds[wv];
    const long long wbase = ((long long)blockIdx.x * 4 + wv) * (16LL * TILES_PER_WAVE);
    if (wbase >= n_tracks) return;   // after the only barrier -> safe

    // ---- W1 frags stay in VGPRs (32 regs, chain head) ----
    s16x8 w1h[4], w1l[4];
    #pragma unroll
    for (int n = 0; n < 4; ++n) load_bfrag(w1, 8 * g, r + 16 * n, w1h[n], w1l[n]);

    float b1v[4], b2v[4];
    #pragma unroll
    for (int n = 0; n < 4; ++n) { b1v[n] = b1[r + 16 * n]; b2v[n] = b2[r + 16 * n]; }

    // ---- prologue loads for tile 0 ----
    long long row0 = wbase + r; if (row0 > n_tracks - 1) row0 = n_tracks - 1;
    f32x4 xa = *(const f32x4*)(x + row0 * N_FEAT + 8 * g);
    f32x4 xb = *(const f32x4*)(x + row0 * N_FEAT + 8 * g + 4);
    long long ib0 = wbase + 4 * g; if (ib0 > n_tracks - 4) ib0 = (n_tracks - 4) & ~3LL;
    i32x4 e4 = *(const i32x4*)(eids + ib0);

    // ---- run-carry pooling state ----
    float carry[4] = {0.f, 0.f, 0.f, 0.f};
    int carry_id = -1;

    #pragma unroll 1
    for (int t = 0; t < TILES_PER_WAVE; ++t) {
        long long tb = wbase + 16LL * t;
        if (tb >= n_tracks) break;

        // ---- convert current x to hi/lo A-frags ----
        s16x8 xh, xl;
        #pragma unroll
        for (int j = 0; j < 4; ++j) {
            short h0 = bfs(xa[j]); xh[j] = h0;     xl[j] = bfs(xa[j] - bff(h0));
            short h1 = bfs(xb[j]); xh[4 + j] = h1; xl[4 + j] = bfs(xb[j] - bff(h1));
        }

        // ---- prefetch tile t+1 ----
        f32x4 xa2, xb2; i32x4 e42;
        const bool pf = (t + 1 < TILES_PER_WAVE) && (tb + 16 < n_tracks);
        if (pf) {
            long long rowp = tb + 16 + r; if (rowp > n_tracks - 1) rowp = n_tracks - 1;
            xa2 = *(const f32x4*)(x + rowp * N_FEAT + 8 * g);
            xb2 = *(const f32x4*)(x + rowp * N_FEAT + 8 * g + 4);
            long long ibp = tb + 16 + 4 * g; if (ibp > n_tracks - 4) ibp = (n_tracks - 4) & ~3LL;
            e42 = *(const i32x4*)(eids + ibp);
        }

        // ---- layer 1: 12 MFMA ----
        f32x4 h1C[4];
        #pragma unroll
        for (int n = 0; n < 4; ++n) {
            f32x4 c = {0.f, 0.f, 0.f, 0.f};
            c = mfma16(xl, w1h[n], c);
            c = mfma16(xh, w1l[n], c);
            c = mfma16(xh, w1h[n], c);
            h1C[n] = c;
        }

        // ---- bias+relu, stage h1 to LDS ----
        #pragma unroll
        for (int n = 0; n < 4; ++n) {
            #pragma unroll
            for (int q = 0; q < 4; ++q) {
                float f = fmaxf(h1C[n][q] + b1v[n], 0.f);
                lds[(4 * g + q) * LDSW + r + 16 * n] = f;
            }
        }

        // ---- layer 2: per-s group {W2 frags from LDS, h1 A-frag, 12 MFMA} ----
        f32x4 h2C[4] = {{0.f,0.f,0.f,0.f},{0.f,0.f,0.f,0.f},{0.f,0.f,0.f,0.f},{0.f,0.f,0.f,0.f}};
        #pragma unroll 1
        for (int s = 0; s < 2; ++s) {
            f32x4 av = *(const f32x4*)&lds[r * LDSW + 32 * s + 8 * g];
            f32x4 bv = *(const f32x4*)&lds[r * LDSW + 32 * s + 8 * g + 4];
            s16x8 ah, al;
            #pragma unroll
            for (int j = 0; j < 4; ++j) {
                short h0 = bfs(av[j]); ah[j] = h0;     al[j] = bfs(av[j] - bff(h0));
                short h1 = bfs(bv[j]); ah[4 + j] = h1; al[4 + j] = bfs(bv[j] - bff(h1));
            }
            #pragma unroll
            for (int n = 0; n < 4; ++n) {
                s16x8 wh = wfrag[4 * s + n][lane];
                s16x8 wl = wfrag[8 + 4 * s + n][lane];
                h2C[n] = mfma16(al, wh, h2C[n]);
                h2C[n] = mfma16(ah, wl, h2C[n]);
                h2C[n] = mfma16(ah, wh, h2C[n]);
            }
        }

        // ---- bias+relu+pool with cross-tile run carry ----
        const int rem = (int)((n_tracks - tb < 16) ? (n_tracks - tb) : 16);
        const bool newrun   = (e4[0] != carry_id);
        const bool doflush0 = newrun && (carry_id >= 0);
        const bool b01 = (e4[1] != e4[0]);
        const bool b12 = (e4[2] != e4[1]);
        const bool b23 = (e4[3] != e4[2]);
        #pragma unroll
        for (int n = 0; n < 4; ++n) {
            f32x4 hv;
            #pragma unroll
            for (int q = 0; q < 4; ++q) {
                float f = fmaxf(h2C[n][q] + b2v[n], 0.f);
                hv[q] = (4 * g + q < rem) ? f : 0.f;
            }
            float* pp = pooled + (size_t)(r + 16 * n);
            float c = carry[n];
            if (doflush0) atomicAdd(pp + (size_t)carry_id * N_LAT, c);
            if (newrun)   c = 0.f;
            c += hv[0];
            if (b01) { atomicAdd(pp + (size_t)e4[0] * N_LAT, c); c = 0.f; }
            c += hv[1];
            if (b12) { atomicAdd(pp + (size_t)e4[1] * N_LAT, c); c = 0.f; }
            c += hv[2];
            if (b23) { atomicAdd(pp + (size_t)e4[2] * N_LAT, c); c = 0.f; }
            c += hv[3];
            carry[n] = c;
        }
        carry_id = e4[3];

        if (pf) { xa = xa2; xb = xb2; e4 = e42; }
    }

    if (carry_id >= 0) {
        #pragma unroll
        for (int n = 0; n < 4; ++n)
            atomicAdd(pooled + (size_t)carry_id * N_LAT + r + 16 * n, carry[n]);
    }
}

// ---------------------------------------------------------------------------
// rho, wave-parallel (unchanged): one wave = 8 events; lane j owns output j
// (and j+64 in layer 1); weights from LDS, broadcasts via readlane.
// ---------------------------------------------------------------------------
__global__ __launch_bounds__(256) void rho_kernel(
    const float* __restrict__ pooled,
    const float* __restrict__ w1, const float* __restrict__ b1,
    const float* __restrict__ w2, const float* __restrict__ b2,
    const float* __restrict__ w3, const float* __restrict__ b3,
    float* __restrict__ out, int n_events)
{
    __shared__ float lw1[N_LAT * R_HID];
    __shared__ float lw2[R_HID * N_LAT];
    __shared__ float lbias[R_HID + N_LAT + N_LAT + 1];
    {
        int tid = threadIdx.x;
        for (int i = tid; i < N_LAT * R_HID; i += 256) lw1[i] = w1[i];
        for (int i = tid; i < R_HID * N_LAT; i += 256) lw2[i] = w2[i];
        if (tid < R_HID) lbias[tid] = b1[tid];
        if (tid < N_LAT) lbias[R_HID + tid] = b2[tid];
        if (tid < N_LAT) lbias[R_HID + N_LAT + tid] = w3[tid];
        if (tid == 0)    lbias[R_HID + 2 * N_LAT] = b3[0];
    }
    __syncthreads();

    const int lane = threadIdx.x & 63;
    const long long ebase = ((long long)blockIdx.x * 4 + (threadIdx.x >> 6)) * 8;
    if (ebase >= n_events) return;

    const float b1va = lbias[lane];
    const float b1vb = lbias[64 + lane];
    const float b2v  = lbias[R_HID + lane];
    const float w3v  = lbias[R_HID + N_LAT + lane];
    const float b3v  = lbias[R_HID + 2 * N_LAT];

    float pe[8];
    #pragma unroll
    for (int i = 0; i < 8; ++i) {
        long long e = ebase + i;
        pe[i] = (e < n_events) ? pooled[e * N_LAT + lane] : 0.f;
    }

    float r1a[8], r1b[8];
    #pragma unroll
    for (int i = 0; i < 8; ++i) { r1a[i] = b1va; r1b[i] = b1vb; }
    #pragma unroll 2
    for (int k = 0; k < N_LAT; ++k) {
        float wA = lw1[k * R_HID + lane];
        float wB = lw1[k * R_HID + 64 + lane];
        #pragma unroll
        for (int i = 0; i < 8; ++i) {
            float s = rdlane(pe[i], k);
            r1a[i] = fmaf(s, wA, r1a[i]);
            r1b[i] = fmaf(s, wB, r1b[i]);
        }
    }
    #pragma unroll
    for (int i = 0; i < 8; ++i) {
        r1a[i] = fmaxf(r1a[i], 0.f);
        r1b[i] = fmaxf(r1b[i], 0.f);
    }

    float r2[8];
    #pragma unroll
    for (int i = 0; i < 8; ++i) r2[i] = b2v;
    #pragma unroll 2
    for (int k = 0; k < 64; ++k) {
        float w = lw2[k * N_LAT + lane];
        #pragma unroll
        for (int i = 0; i < 8; ++i) r2[i] = fmaf(rdlane(r1a[i], k), w, r2[i]);
    }
    #pragma unroll 2
    for (int k = 0; k < 64; ++k) {
        float w = lw2[(64 + k) * N_LAT + lane];
        #pragma unroll
        for (int i = 0; i < 8; ++i) r2[i] = fmaf(rdlane(r1b[i], k), w, r2[i]);
    }

    float zv = 0.f;
    #pragma unroll
    for (int i = 0; i < 8; ++i) {
        float tv = fmaxf(r2[i], 0.f) * w3v;
        #pragma unroll
        for (int off = 32; off >= 1; off >>= 1) tv += __shfl_xor(tv, off, 64);
        zv = (lane == i) ? tv : zv;
    }
    if (lane < 8 && ebase + lane < n_events)
        out[ebase + lane] = 1.f / (1.f + expf(-(zv + b3v)));
}

extern "C" void kernel_launch(void* const* d_in, const int* in_sizes, int n_in,
                              void* d_out, int out_size, void* d_ws, size_t ws_size,
                              hipStream_t stream) {
    const float* x      = (const float*)d_in[0];
    const int*   eids   = (const int*)  d_in[1];
    const float* phi_w1 = (const float*)d_in[2];
    const float* phi_b1 = (const float*)d_in[3];
    const float* phi_w2 = (const float*)d_in[4];
    const float* phi_b2 = (const float*)d_in[5];
    const float* rho_w1 = (const float*)d_in[6];
    const float* rho_b1 = (const float*)d_in[7];
    const float* rho_w2 = (const float*)d_in[8];
    const float* rho_b2 = (const float*)d_in[9];
    const float* rho_w3 = (const float*)d_in[10];
    const float* rho_b3 = (const float*)d_in[11];
    float* out = (float*)d_out;

    int n_tracks = in_sizes[1];
    int n_events = out_size;

    float* pooled = (float*)d_ws;  // [n_events, 64] accumulator
    hipMemsetAsync(pooled, 0, (size_t)n_events * N_LAT * sizeof(float), stream);

    long long tracks_per_wave = 16LL * TILES_PER_WAVE;
    long long waves  = ((long long)n_tracks + tracks_per_wave - 1) / tracks_per_wave;
    int phi_blocks   = (int)((waves + 3) / 4);
    phi_mfma_kernel<<<phi_blocks, 256, 0, stream>>>(
        x, eids, phi_w1, phi_b1, phi_w2, phi_b2, pooled, n_tracks);

    long long ewaves = ((long long)n_events + 7) / 8;
    int rho_blocks = (int)((ewaves + 3) / 4);
    rho_kernel<<<rho_blocks, 256, 0, stream>>>(
        pooled, rho_w1, rho_b1, rho_w2, rho_b2, rho_w3, rho_b3, out, n_events);
}